// Round 2
// baseline (803.973 us; speedup 1.0000x reference)
//
#include <hip/hip_runtime.h>

// MOGCN on MI355X. Pipeline:
//  k_build_wb : W[3,3,512,256] (+ W@a1, W@a2 cols) -> bf16, k-swizzled [64][2432][8]
//  k_xconv    : X fp32 -> bf16, k-swizzled [64][16384][8]
//  k_bitpack  : adj>0 -> bitset masks (level0), two layouts (R9: 16 elems/thread)
//  k_boolmm   : boolean matrix power masks (adj^2>0, adj^3>0) via u64 OR-gather
//  k_gemm_h   : [16384,512]@[512,2432] bf16 MFMA -> h (swizzled) + f1L/f2L (=f·log2e)
//  k_etab     : e1k=2^f2L, e2k=2^(0.2 f2L) per (s,b,k)  (linear-domain tables)
//  k_rowstats : log2-domain softmax stats -> per-row E1=2^(f1L+C), E2=2^(0.2 f1L+C),
//               PZ=2^Z2 (0 for non-empty rows)
//  k_attgemm  : R10 = R9 P-gen (transcendental-free) + NEW sync structure:
//               3-slot LDS ring staged 2 halves ahead, counted vmcnt(9) + raw
//               s_barrier (no vmcnt(0) drain per iteration - was the R7/R9 null
//               explanation: staged-load L2 latency sat on the per-iteration
//               critical path, masking both LDS and VALU savings). All P-gen
//               inputs (e-tables, masks, per-t row consts) prefetched into regs.
//               vmcnt ledger: each half issues exactly [E x4, M x1, cp x4] = 9;
//               >=9 issues follow cp(h) in any ordering => vmcnt(9) proves cp(h)
//               landed while cp(h+1),cp(h+2) stay in flight.
//  k_score    : s = tanh(H@Ww+bw)@Wc  (MFMA GEMM)
//  k_combine  : softmax over layers, weighted sum -> out
//
// Workspace map (bytes), total 159,842,304 (~152.4 MiB):
//  [0)            Xs bf16 16,777,216 | Wb bf16 @16,777,216 (2,490,368)  -- dead after k_gemm_h
//  [0)            H32 fp32 50,331,648 (reuses region above; fully written by k_attgemm)
//  [50,331,648)   hsw bf16 75,497,472   [9][16][128][256][8]
//  [125,829,120)  mbA u64 12,582,912; lvl0 dead after boolmm-1 -> rowE1/rowE2/rowPZ
//  [138,412,032)  mbT u64 18,874,368    [9][16][16w][1024i]
//  [157,286,400)  fbuf fp32 1,179,648   [2][9][16384]  (values pre-scaled by log2e)
//  [158,466,048)  etab1 589,824 | [159,055,872) etab2 589,824 | [159,645,696) svals 196,608

typedef unsigned long long u64;
typedef __attribute__((ext_vector_type(4))) float f32x4;
typedef __attribute__((ext_vector_type(8))) short bf16x8;

#define NEGF (-9.0e15f)
#define L2E 1.44269504f

__device__ __forceinline__ float fexp2(float x){
#if __has_builtin(__builtin_amdgcn_exp2f)
  return __builtin_amdgcn_exp2f(x);
#else
  return exp2f(x);
#endif
}
__device__ __forceinline__ float flog2(float x){
#if __has_builtin(__builtin_amdgcn_logf)
  return __builtin_amdgcn_logf(x);
#else
  return log2f(x);
#endif
}
__device__ __forceinline__ float frcp(float x){
#if __has_builtin(__builtin_amdgcn_rcpf)
  return __builtin_amdgcn_rcpf(x);
#else
  return 1.0f/x;
#endif
}
__device__ __forceinline__ unsigned short f2bf(float x){   // RNE
  union { float f; unsigned u; } a; a.f = x;
  unsigned r = a.u + 0x7FFFu + ((a.u >> 16) & 1u);
  return (unsigned short)(r >> 16);
}
__device__ __forceinline__ float bf2f(unsigned short h){
  union { unsigned u; float f; } a; a.u = ((unsigned)h) << 16; return a.f;
}
__device__ __forceinline__ unsigned pack_bf16x2(float lo, float hi){ // fast round
  union { float f; unsigned u; } a, b; a.f = lo; b.f = hi;
  unsigned ul = a.u + 0x8000u, uh = b.u + 0x8000u;
#if __has_builtin(__builtin_amdgcn_perm)
  return __builtin_amdgcn_perm(uh, ul, 0x07060302u);
#else
  return (ul >> 16) | (uh & 0xFFFF0000u);
#endif
}
__device__ __forceinline__ float tanh_fast(float x){
  float e = fexp2(x * 2.885390082f);  // exp(2x)
  return 1.0f - 2.0f*frcp(e + 1.0f);
}
__device__ __forceinline__ void async_cp16(void* lds, const void* g){
  __builtin_amdgcn_global_load_lds(
      (const __attribute__((address_space(1))) unsigned int*)g,
      (__attribute__((address_space(3))) unsigned int*)lds, 16, 0, 0);
}

// ---------------- prep kernels ----------------

__global__ void k_build_wb(const float* __restrict__ W, const float* __restrict__ a1,
                           const float* __restrict__ a2, unsigned short* __restrict__ Wb)
{
  int idx = blockIdx.x*256 + threadIdx.x;           // g*2432 + c
  if (idx >= 64*2432) return;
  int c = idx % 2432, g = idx / 2432;
  unsigned short o[8];
  if (c < 2304) {
    int s = c >> 8, f = c & 255, t = s % 3, klq = s / 3;   // s = kl*3 + t
    const float* wp = W + ((size_t)(t*3 + klq)*512)*256 + f;
#pragma unroll
    for (int e = 0; e < 8; ++e) o[e] = f2bf(wp[(size_t)(g*8 + e)*256]);
  } else if (c < 2322) {
    int c2 = c - 2304, s = c2 >> 1, t = s % 3, klq = s / 3;
    const float* av = ((c2 & 1) ? a2 : a1) + (t*3 + klq)*256;
    const float* wp = W + ((size_t)(t*3 + klq)*512)*256;
#pragma unroll
    for (int e = 0; e < 8; ++e) {
      float acc = 0.0f;
      const float* wr = wp + (size_t)(g*8 + e)*256;
      for (int f = 0; f < 256; ++f) acc += wr[f]*av[f];
      o[e] = f2bf(acc);
    }
  } else {
#pragma unroll
    for (int e = 0; e < 8; ++e) o[e] = 0;
  }
  ushort4 lo, hi;
  lo.x=o[0]; lo.y=o[1]; lo.z=o[2]; lo.w=o[3];
  hi.x=o[4]; hi.y=o[5]; hi.z=o[6]; hi.w=o[7];
  ushort4* dst = (ushort4*)(Wb + (size_t)idx*8);
  dst[0] = lo; dst[1] = hi;
}

__global__ void k_xconv(const float* __restrict__ X, unsigned short* __restrict__ Xs)
{
  int idx = blockIdx.x*256 + threadIdx.x;           // g*16384 + bn
  int bn = idx & 16383, g = idx >> 14;
  const float* xp = X + (size_t)bn*512 + g*8;
  ushort4 lo, hi;
  lo.x=f2bf(xp[0]); lo.y=f2bf(xp[1]); lo.z=f2bf(xp[2]); lo.w=f2bf(xp[3]);
  hi.x=f2bf(xp[4]); hi.y=f2bf(xp[5]); hi.z=f2bf(xp[6]); hi.w=f2bf(xp[7]);
  ushort4* dst = (ushort4*)(Xs + (size_t)idx*8);
  dst[0] = lo; dst[1] = hi;
}

// 16 elements per thread (grid 12288) to amortize wave launch/retire.
__global__ void k_bitpack(const float* __restrict__ adj, u64* __restrict__ mbA0,
                          u64* __restrict__ mbT)
{
  const size_t stride = (size_t)12288*256;
  size_t tid0 = (size_t)blockIdx.x*256 + threadIdx.x;
  float v[16];
#pragma unroll
  for (int r = 0; r < 16; ++r) v[r] = adj[tid0 + (size_t)r*stride];
#pragma unroll
  for (int r = 0; r < 16; ++r) {
    u64 msk = __ballot(v[r] > 0.0f);
    if ((threadIdx.x & 63) == 0) {
      size_t word = (tid0 + (size_t)r*stride) >> 6;
      int w = (int)(word & 15), i = (int)((word >> 4) & 1023);
      int bt = (int)(word >> 14);     // b*3 + t
      int t = bt % 3, b = bt / 3;
      mbA0[((size_t)(t*16 + b)*1024 + i)*16 + w] = msk;
      mbT[(((size_t)t*16 + b)*16 + w)*1024 + i] = msk;   // s = t for level 0
    }
  }
}

__global__ void k_boolmm(const u64* __restrict__ A, const u64* __restrict__ Bm,
                         u64* __restrict__ outA, u64* __restrict__ outT, int sbase)
{
  int tid = blockIdx.x*256 + threadIdx.x;   // 48*1024*16
  int w = tid & 15, i = (tid >> 4) & 1023, tb = tid >> 14;
  const u64* Ar = A + ((size_t)tb*1024 + i)*16;
  const u64* Bb = Bm + (size_t)tb*16384;
  u64 acc = 0;
  for (int ww = 0; ww < 16; ++ww) {
    u64 aw = Ar[ww];
    while (aw) {
      int kk = __builtin_ctzll(aw);
      aw &= aw - 1;
      acc |= Bb[((size_t)(ww*64 + kk))*16 + w];
    }
  }
  if (outA) outA[((size_t)tb*1024 + i)*16 + w] = acc;
  int t = tb >> 4, bq = tb & 15;
  outT[(((size_t)(sbase + t)*16 + bq)*16 + w)*1024 + i] = acc;
}

// ---------------- h = X@W GEMM (bf16 MFMA), fused f1L/f2L (pre-scaled log2e) -------

__global__ __launch_bounds__(256) void k_gemm_h(
    const unsigned short* __restrict__ Xs, const unsigned short* __restrict__ Wb,
    unsigned short* __restrict__ hsw, float* __restrict__ fbuf)
{
  __shared__ unsigned short Asl[8*132*8 + 8];
  __shared__ unsigned short Bsl[8*132*8 + 8];
  const int tid = threadIdx.x, lane = tid & 63, wid = tid >> 6;
  int vb = blockIdx.x;                       // XCD swizzle: same mt -> same XCD
  int xc = vb & 7, mrest = vb >> 3;
  int mt = xc + 8*(mrest/19), nt = mrest % 19;
  const int M0 = mt << 7, N0 = nt << 7;
  const int wr = (wid >> 1) << 6, wc = (wid & 1) << 6;
  const int me = lane & 15;
  f32x4 acc[4][4] = {};
  for (int ks64 = 0; ks64 < 8; ++ks64) {
    __syncthreads();
#pragma unroll
    for (int c = 0; c < 4; ++c) {
      int chunk = wid*4 + c, g = chunk >> 1, hh = chunk & 1;
      int ldsoff = (g*132 + hh*64)*8;
      const unsigned short* gpA = Xs + ((size_t)(ks64*8 + g)*16384 + (M0 + hh*64 + lane))*8;
      async_cp16(Asl + ldsoff, gpA);
      const unsigned short* gpB = Wb + ((size_t)(ks64*8 + g)*2432 + (N0 + hh*64 + lane))*8;
      async_cp16(Bsl + ldsoff, gpB);
    }
    __syncthreads();
#pragma unroll
    for (int ks32 = 0; ks32 < 2; ++ks32) {
      const int kg = ks32*4 + (lane >> 4);
      bf16x8 afr[4], bfr[4];
#pragma unroll
      for (int rb = 0; rb < 4; ++rb)
        afr[rb] = *(const bf16x8*)(Asl + (kg*132 + wr + rb*16 + me)*8);
#pragma unroll
      for (int cb = 0; cb < 4; ++cb)
        bfr[cb] = *(const bf16x8*)(Bsl + (kg*132 + wc + cb*16 + me)*8);
#pragma unroll
      for (int rb = 0; rb < 4; ++rb)
#pragma unroll
        for (int cb = 0; cb < 4; ++cb)
          acc[rb][cb] = __builtin_amdgcn_mfma_f32_16x16x32_bf16(afr[rb], bfr[cb], acc[rb][cb], 0, 0, 0);
    }
  }
  const int quad = lane >> 4;
#pragma unroll
  for (int rb = 0; rb < 4; ++rb) {
    int jbase = M0 + wr + rb*16 + quad*4;
    int bidx = jbase >> 10, jn = jbase & 1023;
#pragma unroll
    for (int cb = 0; cb < 4; ++cb) {
      int c = N0 + wc + cb*16 + me;
      f32x4 v = acc[rb][cb];
      if (c < 2304) {
        int s = c >> 8, f = c & 255;
        ushort4 pk;
        pk.x = f2bf(v[0]); pk.y = f2bf(v[1]); pk.z = f2bf(v[2]); pk.w = f2bf(v[3]);
        *(ushort4*)(hsw + (size_t)s*4194304 + (size_t)bidx*262144 + ((jn>>3)*256 + f)*8 + (jn&7)) = pk;
      } else if (c < 2322) {
        int c2 = c - 2304, s = c2 >> 1, wh = c2 & 1;
        *(f32x4*)(fbuf + (size_t)wh*147456 + s*16384 + jbase) = v * L2E;  // log2 domain
      }
    }
  }
}

// ---------------- per-k linear-domain tables ----------------

__global__ void k_etab(const float* __restrict__ fbuf,
                       float* __restrict__ et1, float* __restrict__ et2)
{
  int idx = blockIdx.x*256 + threadIdx.x;   // 576*256 = 147456
  float f2L = fbuf[147456 + idx];
  et1[idx] = fexp2(f2L);
  et2[idx] = fexp2(0.2f*f2L);
}

// ---------------- per-row softmax stats (log2 domain internally) ----------------

__global__ __launch_bounds__(256) void k_rowstats(
    const u64* __restrict__ mbT, const float* __restrict__ fbuf,
    float* __restrict__ rowE1, float* __restrict__ rowE2, float* __restrict__ rowPZ)
{
  int gw = blockIdx.x*4 + (threadIdx.x >> 6);   // row id: (s*16+b)*1024 + i
  int lane = threadIdx.x & 63;
  int i = gw & 1023, sb = gw >> 10;
  int b = sb & 15, s = sb >> 4;
  const u64* mrow = mbT + (size_t)sb*16384 + i;
  const float* f1g = fbuf + s*16384 + b*1024;
  const float* f2g = fbuf + 147456 + s*16384 + b*1024;
  float f1i = f1g[i];
  float vals[16];
  float mmax = NEGF;
#pragma unroll
  for (int w = 0; w < 16; ++w) {
    u64 word = mrow[(size_t)w*1024];
    float u0 = f1i + f2g[w*64 + lane];          // (f1+f2)*log2e
    float lk = fmaxf(u0, 0.2f*u0);              // leaky in log2 domain
    float val = ((word >> lane) & 1ull) ? lk : NEGF;
    vals[w] = val;
    mmax = fmaxf(mmax, val);
  }
#pragma unroll
  for (int off = 32; off; off >>= 1) mmax = fmaxf(mmax, __shfl_xor(mmax, off));
  float l = 0.0f;
#pragma unroll
  for (int w = 0; w < 16; ++w) l += fexp2(vals[w] - mmax);
#pragma unroll
  for (int off = 32; off; off >>= 1) l += __shfl_xor(l, off);
  if (lane == 0) {
    bool empty = (mmax < -8.0e15f);
    float C = (empty ? 0.0f : -mmax) - flog2(l);
    rowE1[gw] = fexp2(f1i + C);
    rowE2[gw] = fexp2(0.2f*f1i + C);
    rowPZ[gw] = empty ? fexp2(C) : 0.0f;        // exact 0 for non-empty rows
  }
}

// ---------------- fused attention GEMM: H = sum_t softmax(mask_t(e_t)) @ h_t --------
// R10: 3-slot ring + counted vmcnt, details in header comment.

__global__ __launch_bounds__(256, 3) void k_attgemm(
    const unsigned short* __restrict__ hsw,
    const float* __restrict__ et1g, const float* __restrict__ et2g,
    const float* __restrict__ rowE1, const float* __restrict__ rowE2,
    const float* __restrict__ rowPZ,
    const u64* __restrict__ mbT, float* __restrict__ H32)
{
  __shared__ unsigned short Bts[3*4*260*8];   // 3-slot ring, 16640 B per slot
  const int tid = threadIdx.x, lane = tid & 63, wid = tid >> 6;
  const int me = lane & 15, quad = lane >> 4;
  int vb = blockIdx.x;
  int mt = vb / 48, g = vb % 48;              // g%8 constant across a group's 16 blocks
  int kl = g >> 4, b = g & 15;
  const int i0w = mt*64 + wid*16;
  const int ir0 = i0w + me;
  const unsigned short* hbase = hsw + (size_t)(kl*3)*4194304 + (size_t)b*262144;
  const float* e1b = et1g + (kl*3)*16384 + b*1024;   // e1k table
  const float* e2b = et2g + (kl*3)*16384 + b*1024;   // e2k table
  const float* E1b = rowE1 + ((kl*3)*16 + b)*1024;
  const float* E2b = rowE2 + ((kl*3)*16 + b)*1024;
  const float* PZb = rowPZ + ((kl*3)*16 + b)*1024;
  const u64* mb = mbT + (size_t)((kl*3)*16 + b)*16384;   // t-stride 262144 u64

  f32x4 acc[16] = {};

  // ---- prologue ----
  // cp(0) into slot 0
  {
    const unsigned short* hstage = hbase + wid*2048;
    unsigned short* lb = Bts + wid*2080;
#pragma unroll
    for (int c = 0; c < 4; ++c) async_cp16(lb + c*512, hstage + c*512 + lane*8);
  }
  // per-t row constants for all 3 t (kept in regs for the whole kernel)
  float e1c0 = E1b[ir0], e1c1 = E1b[16384 + ir0], e1c2 = E1b[32768 + ir0];
  float e2c0 = E2b[ir0], e2c1 = E2b[16384 + ir0], e2c2 = E2b[32768 + ir0];
  float pz0  = PZb[ir0], pz1  = PZb[16384 + ir0], pz2  = PZb[32768 + ir0];
  int az0 = __any(pz0 != 0.0f) ? 1 : 0;
  int az1 = __any(pz1 != 0.0f) ? 1 : 0;
  int az2 = __any(pz2 != 0.0f) ? 1 : 0;
  asm volatile("s_waitcnt vmcnt(0)" ::: "memory");   // cp(0) + consts fully landed
  // E(0), M(0) prefetch into regs
  float eA1[8], eA2[8], eB1[8], eB2[8];
  {
    const float* p1 = e1b + quad*8;
    const float* p2 = e2b + quad*8;
    float4 a0 = *(const float4*)(p1), a1 = *(const float4*)(p1+4);
    float4 b0 = *(const float4*)(p2), b1 = *(const float4*)(p2+4);
    eA1[0]=a0.x; eA1[1]=a0.y; eA1[2]=a0.z; eA1[3]=a0.w;
    eA1[4]=a1.x; eA1[5]=a1.y; eA1[6]=a1.z; eA1[7]=a1.w;
    eA2[0]=b0.x; eA2[1]=b0.y; eA2[2]=b0.z; eA2[3]=b0.w;
    eA2[4]=b1.x; eA2[5]=b1.y; eA2[6]=b1.z; eA2[7]=b1.w;
  }
  u64 mAv = mb[ir0], mBv = 0;
  // cp(1) into slot 1
  {
    const unsigned short* hstage = hbase + (4 + wid)*2048;
    unsigned short* lb = Bts + 8320 + wid*2080;
#pragma unroll
    for (int c = 0; c < 4; ++c) async_cp16(lb + c*512, hstage + c*512 + lane*8);
  }

  unsigned short *sA = Bts, *sB = Bts + 8320, *sC = Bts + 16640;
  float E1v = 0.0f, E2v = 0.0f, PZv = 0.0f;
  int anyPZ = 0;

  // one half-iteration: wait ring / barrier / issue next prefetches / P-gen / MFMA
#define HALF_STEP(H, EC1, EC2, EN1, EN2, MC, MN)                                \
  {                                                                             \
    asm volatile("s_waitcnt vmcnt(9)" ::: "memory");                            \
    __builtin_amdgcn_s_barrier();                                               \
    __builtin_amdgcn_sched_barrier(0);                                          \
    const int h_ = (H);                                                         \
    int hw_ = h_ + 1; if (hw_ >= 96) hw_ = 0;                                   \
    int tn_ = hw_ >> 5, sn_ = (hw_ >> 1) & 15, kn_ = hw_ & 1;                   \
    { const float* p1_ = e1b + tn_*16384 + sn_*64 + kn_*32 + quad*8;            \
      const float* p2_ = e2b + tn_*16384 + sn_*64 + kn_*32 + quad*8;            \
      float4 a0_ = *(const float4*)(p1_), a1_ = *(const float4*)(p1_+4);        \
      float4 b0_ = *(const float4*)(p2_), b1_ = *(const float4*)(p2_+4);        \
      EN1[0]=a0_.x; EN1[1]=a0_.y; EN1[2]=a0_.z; EN1[3]=a0_.w;                   \
      EN1[4]=a1_.x; EN1[5]=a1_.y; EN1[6]=a1_.z; EN1[7]=a1_.w;                   \
      EN2[0]=b0_.x; EN2[1]=b0_.y; EN2[2]=b0_.z; EN2[3]=b0_.w;                   \
      EN2[4]=b1_.x; EN2[5]=b1_.y; EN2[6]=b1_.z; EN2[7]=b1_.w; }                 \
    MN = mb[(size_t)tn_*262144 + sn_*1024 + ir0];                               \
    { int hn_ = h_ + 2; if (hn_ >= 96) hn_ -= 96;                               \
      int t2_ = hn_ >> 5, s2_ = (hn_ >> 1) & 15, k2_ = hn_ & 1;                 \
      const unsigned short* hst_ = hbase + (size_t)t2_*4194304 + s2_*16384 +    \
                                   (k2_*4 + wid)*2048;                          \
      unsigned short* lb_ = sC + wid*2080;                                      \
      _Pragma("unroll")                                                         \
      for (int c = 0; c < 4; ++c)                                               \
        async_cp16(lb_ + c*512, hst_ + c*512 + lane*8); }                       \
    if ((h_ & 31) == 0) {                                                       \
      int tt_ = h_ >> 5;                                                        \
      E1v = (tt_==0) ? e1c0 : (tt_==1) ? e1c1 : e1c2;                           \
      E2v = (tt_==0) ? e2c0 : (tt_==1) ? e2c1 : e2c2;                           \
      PZv = (tt_==0) ? pz0  : (tt_==1) ? pz1  : pz2;                            \
      anyPZ = (tt_==0) ? az0 : (tt_==1) ? az1 : az2;                            \
    }                                                                           \
    const int kloc_ = (h_ & 1)*32 + quad*8;                                     \
    unsigned mq_ = (unsigned)((MC) >> kloc_);                                   \
    union { bf16x8 v; unsigned u[4]; } ua_;                                     \
    if (!anyPZ) {                                                               \
      _Pragma("unroll")                                                         \
      for (int p = 0; p < 4; ++p) {                                             \
        float pm0_ = fmaxf(EC1[2*p]*E1v,   EC2[2*p]*E2v);                       \
        float pm1_ = fmaxf(EC1[2*p+1]*E1v, EC2[2*p+1]*E2v);                     \
        unsigned m0_ = (unsigned)(-(int)((mq_ >> (2*p))   & 1u));               \
        unsigned m1_ = (unsigned)(-(int)((mq_ >> (2*p+1)) & 1u));               \
        float q0_ = __uint_as_float(m0_ & __float_as_uint(pm0_));               \
        float q1_ = __uint_as_float(m1_ & __float_as_uint(pm1_));               \
        ua_.u[p] = pack_bf16x2(q0_, q1_);                                       \
      }                                                                         \
    } else {                                                                    \
      _Pragma("unroll")                                                         \
      for (int p = 0; p < 4; ++p) {                                             \
        float pm0_ = fmaxf(EC1[2*p]*E1v,   EC2[2*p]*E2v);                       \
        float pm1_ = fmaxf(EC1[2*p+1]*E1v, EC2[2*p+1]*E2v);                     \
        float q0_ = ((mq_ >> (2*p))   & 1u) ? pm0_ : PZv;                       \
        float q1_ = ((mq_ >> (2*p+1)) & 1u) ? pm1_ : PZv;                       \
        ua_.u[p] = pack_bf16x2(q0_, q1_);                                       \
      }                                                                         \
    }                                                                           \
    const unsigned short* bb_ = sA + quad*2080;                                 \
    _Pragma("unroll")                                                           \
    for (int cb = 0; cb < 16; ++cb) {                                           \
      bf16x8 bf_ = *(const bf16x8*)(bb_ + (cb*16 + me)*8);                      \
      acc[cb] = __builtin_amdgcn_mfma_f32_16x16x32_bf16(ua_.v, bf_, acc[cb], 0, 0, 0); \
    }                                                                           \
    unsigned short* tmp_ = sA; sA = sB; sB = sC; sC = tmp_;                     \
  }

  for (int o = 0; o < 48; ++o) {
    HALF_STEP(2*o,     eA1, eA2, eB1, eB2, mAv, mBv)
    HALF_STEP(2*o + 1, eB1, eB2, eA1, eA2, mBv, mAv)
  }
#undef HALF_STEP

  // epilogue: plain stores (each (kl,b,row,f) written exactly once)
  {
    int io = i0w + quad*4;
#pragma unroll
    for (int cb = 0; cb < 16; ++cb) {
      int f = cb*16 + me;
      float* hp = H32 + (((size_t)b*1024 + io)*3 + kl)*256 + f;
#pragma unroll
      for (int r = 0; r < 4; ++r)
        hp[(size_t)r*768] = acc[cb][r];
    }
  }
}

// ---------------- layer attention: s = tanh(H@Ww+bw)@Wc (MFMA) ----------------

__global__ __launch_bounds__(256) void k_score(
    const float* __restrict__ H32, const float* __restrict__ Ww,
    const float* __restrict__ bwv, const float* __restrict__ Wcv, float* __restrict__ svals)
{
  __shared__ unsigned short Bs[8*7*64*8];   // 57344 B
  __shared__ float bwL[128], WcL[128];
  const int tid = threadIdx.x, lane = tid & 63, wid = tid >> 6;
  const int me = lane & 15, quad = lane >> 4;
  for (int idx = tid; idx < 3584; idx += 256) {
    int kk = idx / 448, rem = idx % 448;
    int cb = rem >> 6, l = rem & 63;
    int n = cb*16 + (l & 15);
    int kbase = kk*32 + (l >> 4)*8;
    ushort4 lo, hi;
    if (n < 100) {
      const float* wp = Ww + (size_t)kbase*100 + n;
      lo.x = f2bf(wp[0]);   lo.y = f2bf(wp[100]); lo.z = f2bf(wp[200]); lo.w = f2bf(wp[300]);
      hi.x = f2bf(wp[400]); hi.y = f2bf(wp[500]); hi.z = f2bf(wp[600]); hi.w = f2bf(wp[700]);
    } else {
      lo.x=lo.y=lo.z=lo.w=0; hi.x=hi.y=hi.z=hi.w=0;
    }
    ushort4* dst = (ushort4*)(Bs + (size_t)idx*8);
    dst[0] = lo; dst[1] = hi;
  }
  if (tid < 128) {
    bwL[tid] = (tid < 100) ? bwv[tid] : 0.0f;
    WcL[tid] = (tid < 100) ? Wcv[tid] : 0.0f;
  }
  __syncthreads();

  const int row0 = blockIdx.x*64 + wid*16;
  const float* Arow = H32 + (size_t)(row0 + me)*256;
  f32x4 acc[7] = {};
#pragma unroll
  for (int kk = 0; kk < 8; ++kk) {
    const float* ap = Arow + kk*32 + quad*8;
    float4 a0 = *(const float4*)(ap);
    float4 a1 = *(const float4*)(ap + 4);
    union { bf16x8 v; unsigned u[4]; } ua;
    ua.u[0] = pack_bf16x2(a0.x, a0.y);
    ua.u[1] = pack_bf16x2(a0.z, a0.w);
    ua.u[2] = pack_bf16x2(a1.x, a1.y);
    ua.u[3] = pack_bf16x2(a1.z, a1.w);
#pragma unroll
    for (int cb = 0; cb < 7; ++cb) {
      bf16x8 bf = *(const bf16x8*)(Bs + ((size_t)(kk*7 + cb)*64 + lane)*8);
      acc[cb] = __builtin_amdgcn_mfma_f32_16x16x32_bf16(ua.v, bf, acc[cb], 0, 0, 0);
    }
  }
#pragma unroll
  for (int r = 0; r < 4; ++r) {
    float contrib = 0.0f;
#pragma unroll
    for (int cb = 0; cb < 7; ++cb) {
      int col = cb*16 + me;
      contrib += tanh_fast(acc[cb][r] + bwL[col]) * WcL[col];
    }
    contrib += __shfl_xor(contrib, 1);
    contrib += __shfl_xor(contrib, 2);
    contrib += __shfl_xor(contrib, 4);
    contrib += __shfl_xor(contrib, 8);
    if (me == 0) svals[row0 + quad*4 + r] = contrib;
  }
}

__global__ void k_combine(const float* __restrict__ svals, const float* __restrict__ H32,
                          float* __restrict__ out)
{
  int tid = blockIdx.x*256 + threadIdx.x;
  int fq = tid & 63, bn = tid >> 6;
  float s0 = svals[bn*3], s1 = svals[bn*3+1], s2 = svals[bn*3+2];
  float mm = fmaxf(s0, fmaxf(s1, s2));
  float e0 = fexp2((s0-mm)*L2E), e1 = fexp2((s1-mm)*L2E), e2 = fexp2((s2-mm)*L2E);
  float inv = frcp(e0 + e1 + e2);
  const f32x4* h0 = (const f32x4*)(H32 + (size_t)bn*768) + fq;
  const f32x4* h1 = (const f32x4*)(H32 + (size_t)bn*768 + 256) + fq;
  const f32x4* h2 = (const f32x4*)(H32 + (size_t)bn*768 + 512) + fq;
  f32x4 r = (e0*(*h0) + e1*(*h1) + e2*(*h2))*inv;
  *((f32x4*)out + (size_t)bn*64 + fq) = r;
}

// ---------------- launcher ----------------

extern "C" void kernel_launch(void* const* d_in, const int* in_sizes, int n_in,
                              void* d_out, int out_size, void* d_ws, size_t ws_size,
                              hipStream_t stream) {
  const float* adj = (const float*)d_in[0];
  const float* X   = (const float*)d_in[1];
  const float* W   = (const float*)d_in[2];
  const float* a1  = (const float*)d_in[3];
  const float* a2  = (const float*)d_in[4];
  const float* Ww  = (const float*)d_in[5];
  const float* bw  = (const float*)d_in[6];
  const float* Wc  = (const float*)d_in[7];
  float* out = (float*)d_out;
  char* ws = (char*)d_ws;

  unsigned short* Xs  = (unsigned short*)(ws + 0);
  unsigned short* Wb  = (unsigned short*)(ws + 16777216);
  float* H32          = (float*)(ws + 0);                // reuses Xs/Wb region
  unsigned short* hsw = (unsigned short*)(ws + 50331648);
  u64* mbA            = (u64*)(ws + 125829120);
  float* rowE1        = (float*)(ws + 125829120);        // mbA lvl0, dead after boolmm-1
  float* rowE2        = (float*)(ws + 126418944);
  float* rowPZ        = (float*)(ws + 127008768);
  u64* mbT            = (u64*)(ws + 138412032);
  float* fbuf         = (float*)(ws + 157286400);
  float* etab1        = (float*)(ws + 158466048);
  float* etab2        = (float*)(ws + 159055872);
  float* svals        = (float*)(ws + 159645696);

  k_build_wb<<<608, 256, 0, stream>>>(W, a1, a2, Wb);
  k_xconv<<<4096, 256, 0, stream>>>(X, Xs);
  k_bitpack<<<12288, 256, 0, stream>>>(adj, mbA, mbT);
  k_boolmm<<<3072, 256, 0, stream>>>(mbA, mbA, mbA + 786432, mbT, 3);
  k_boolmm<<<3072, 256, 0, stream>>>(mbA + 786432, mbA, (u64*)nullptr, mbT, 6);
  k_gemm_h<<<2432, 256, 0, stream>>>(Xs, Wb, hsw, fbuf);
  k_etab<<<576, 256, 0, stream>>>(fbuf, etab1, etab2);
  k_rowstats<<<36864, 256, 0, stream>>>(mbT, fbuf, rowE1, rowE2, rowPZ);
  k_attgemm<<<768, 256, 0, stream>>>(hsw, etab1, etab2, rowE1, rowE2, rowPZ, mbT, H32);
  k_score<<<768, 256, 0, stream>>>(H32, Ww, bw, Wc, svals);
  k_combine<<<4096, 256, 0, stream>>>(svals, H32, out);
}